// Round 10
// baseline (144.955 us; speedup 1.0000x reference)
//
#include <hip/hip_runtime.h>
#include <hip/hip_bf16.h>
#include <stdint.h>

#define N_CELLS 196608
#define NH 9
#define F 64            // F_IN == F_OUT == 64
#define K_TOT (NH * F)  // 576
#define BLOCK 512       // 8 waves, 32 cells per wave, 256 cells/block
#define NFRAG (NH * 4)  // 36 B-fragments (j, t)
#define WQ_BYTES (NFRAG * 64 * 16)   // 36864 B
#define LDS_BYTES 65536              // 36KB W + reuse as 64KB epilogue buffer

typedef __attribute__((ext_vector_type(4))) int   i32x4;
typedef __attribute__((ext_vector_type(4))) float f32x4;

// ---------------- x: fp32 -> int8 codes + per-row fp32 scale ---------------
// Plain row layout: byte k = feature k. Row = 64 B = one cache line.
__global__ __launch_bounds__(256) void convert_x_i8(
        const float* __restrict__ x, signed char* __restrict__ xq,
        float* __restrict__ stab) {
    int gid = blockIdx.x * blockDim.x + threadIdx.x;
    int row = gid >> 4;
    int k   = (gid & 15) * 4;
    f32x4 v = *reinterpret_cast<const f32x4*>(x + (size_t)row * F + k);
    float m = fmaxf(fmaxf(fabsf(v[0]), fabsf(v[1])),
                    fmaxf(fabsf(v[2]), fabsf(v[3])));
    #pragma unroll
    for (int d = 1; d < 16; d <<= 1) m = fmaxf(m, __shfl_xor(m, d, 64));
    float rs = (m > 0.f) ? 127.0f / m : 0.f;
    unsigned int d = 0;
    #pragma unroll
    for (int q = 0; q < 4; ++q) {
        int qi = (int)rintf(v[q] * rs);
        d |= ((unsigned int)(qi & 0xff)) << (q * 8);
    }
    *reinterpret_cast<unsigned int*>(xq + (size_t)row * F + k) = d;
    if ((gid & 15) == 0) stab[row] = m * (1.0f / 127.0f);
}

// ---------------- W per-column max -> wscale[64] ---------------------------
__global__ __launch_bounds__(256) void convert_wscale(
        const float* __restrict__ W, float* __restrict__ wscale) {
    __shared__ float mx[64];
    int o = threadIdx.x & 63, chunk = threadIdx.x >> 6;  // 4 threads per col
    if (threadIdx.x < 64) mx[threadIdx.x] = 0.f;
    __syncthreads();
    float m = 0.f;
    for (int k = chunk * 144; k < (chunk + 1) * 144; ++k)
        m = fmaxf(m, fabsf(W[(size_t)k * F + o]));
    atomicMax(reinterpret_cast<int*>(&mx[o]), __float_as_int(m));  // m >= 0
    __syncthreads();
    if (threadIdx.x < 64) wscale[threadIdx.x] = mx[threadIdx.x] * (1.0f / 127.0f);
}

// ---------------- W -> int8 MFMA B-fragment layout -------------------------
// frag id = j*4 + t. Lane l holds 16 bytes: wq[k = j*64 + (l>>4)*16 + b]
// [o = t*16 + (l&15)], b = 0..15.
__global__ __launch_bounds__(256) void convert_wq(
        const float* __restrict__ W, const float* __restrict__ wscale,
        unsigned char* __restrict__ wq) {
    int gid = blockIdx.x * blockDim.x + threadIdx.x;  // 0..2303
    int l = gid & 63, fid = gid >> 6;                 // fid 0..35
    int j = fid >> 2, t = fid & 3;
    int hi = l >> 4, lo = l & 15;
    int o = t * 16 + lo;
    float ws = wscale[o];
    float inv = (ws > 0.f) ? 1.0f / ws : 0.f;
    unsigned int dw[4];
    #pragma unroll
    for (int w = 0; w < 4; ++w) {
        unsigned int d = 0;
        #pragma unroll
        for (int b = 0; b < 4; ++b) {
            int k = j * 64 + hi * 16 + w * 4 + b;
            int qi = (int)rintf(W[(size_t)k * F + o] * inv);
            d |= ((unsigned int)(qi & 0xff)) << (b * 8);
        }
        dw[w] = d;
    }
    *reinterpret_cast<uint4*>(wq + (size_t)gid * 16) =
        make_uint4(dw[0], dw[1], dw[2], dw[3]);
}

// ---------------- fused gather + GEMM, v10: direct int8 MFMA ---------------
// v9 post-mortem: int8->bf16 expand sat BETWEEN load and MFMA (VALU 19%,
// MfmaUtil 7.7%, dur 72us). v10 feeds the raw 16B gathered codes straight
// into mfma_i32_16x16x64_i8 (K=64 = whole neighbor row, A-frag = the load).
// Per-row scales applied AFTER the MFMA (int32 tile -> cvt+fma, off the
// load-critical path; 8 shuffles/j to move scales to the C/D layout).
// W int8 per-column scale factors out to the epilogue entirely.
// Gather lines per wave per j: 32 (vs v8's 64). MFMA count halved.
__global__ __launch_bounds__(BLOCK, 2) void fused_gather_gemm_v10(
        const signed char* __restrict__ xq, const float* __restrict__ stab,
        const int* __restrict__ adjc, const unsigned char* __restrict__ wq,
        const float* __restrict__ wscale, float* __restrict__ out) {
    __shared__ __align__(16) unsigned char lds[LDS_BYTES];

    const int wave = threadIdx.x >> 6;
    const int lane = threadIdx.x & 63;
    const int lo = lane & 15, hi = lane >> 4;
    const int wcell = blockIdx.x * 256 + wave * 32;  // wave's 32 cells

    // --- neighbor indices + per-row scales (stab: 0.8MB, L2-resident)
    int   idx[2][NH];
    float sc[2][NH];
    #pragma unroll
    for (int m = 0; m < 2; ++m) {
        const int* ap = adjc + (size_t)(wcell + m * 16 + lo) * NH;
        #pragma unroll
        for (int j = 0; j < NH; ++j) idx[m][j] = __builtin_nontemporal_load(ap + j);
        #pragma unroll
        for (int j = 0; j < NH; ++j) sc[m][j] = stab[idx[m][j]];
    }

    // one 16B load = lane's complete A-fragment (k = hi*16 .. hi*16+15)
    auto loadA = [&](int m, int j) -> i32x4 {
        return *reinterpret_cast<const i32x4*>(
                xq + (size_t)idx[m][j] * F + hi * 16);
    };

    // --- stage W fragments into LDS (2304 x 16B, coalesced)
    {
        const i32x4* src = reinterpret_cast<const i32x4*>(wq);
        i32x4* dst = reinterpret_cast<i32x4*>(lds);
        #pragma unroll
        for (int it = 0; it < 5; ++it) {
            int i = it * BLOCK + threadIdx.x;
            if (i < NFRAG * 64) dst[i] = src[i];
        }
    }

    // --- ring prologue: issue A(0), A(1)
    i32x4 aS[3][2];
    #pragma unroll
    for (int m = 0; m < 2; ++m) {
        aS[0][m] = loadA(m, 0);
        aS[1][m] = loadA(m, 1);
    }
    __syncthreads();

    f32x4 acc[2][4];
    #pragma unroll
    for (int m = 0; m < 2; ++m)
        #pragma unroll
        for (int t = 0; t < 4; ++t) acc[m][t] = f32x4{0.f, 0.f, 0.f, 0.f};

    const i32x4* wl = reinterpret_cast<const i32x4*>(lds);
    const int sbase = (lane >> 4) * 20;  // hi*16 + hi*4: shfl src for row hi*4+r

    #pragma unroll
    for (int j = 0; j < NH; ++j) {
        const int cur = j % 3;            // compile-time after full unroll
        const int nxt = (j + 2) % 3;
        if (j + 2 < NH) {                 // issue slice j+2's 2 gathers
            #pragma unroll
            for (int m = 0; m < 2; ++m) aS[nxt][m] = loadA(m, j + 2);
        }
        __builtin_amdgcn_sched_barrier(0);   // loads issued above stay above

        // scales for this j in C/D layout: row = hi*4 + r
        float sd[2][4];
        #pragma unroll
        for (int m = 0; m < 2; ++m)
            #pragma unroll
            for (int r = 0; r < 4; ++r)
                sd[m][r] = __shfl(sc[m][j], sbase + r, 64);

        #pragma unroll
        for (int t = 0; t < 4; ++t) {
            i32x4 b = wl[(j * 4 + t) * 64 + lane];   // ds_read_b128, conflict-free
            #pragma unroll
            for (int m = 0; m < 2; ++m) {
                i32x4 iz = {0, 0, 0, 0};
                i32x4 iacc = __builtin_amdgcn_mfma_i32_16x16x64_i8(
                        aS[cur][m], b, iz, 0, 0, 0);
                #pragma unroll
                for (int r = 0; r < 4; ++r)
                    acc[m][t][r] += sd[m][r] * (float)iacc[r];  // post-MFMA dequant
            }
        }
        __builtin_amdgcn_sched_barrier(0);   // MFMAs can't float up
    }

    // --- epilogue: x wscale[o], transpose through LDS, 1KB coalesced stores
    float wsc[4];
    #pragma unroll
    for (int t = 0; t < 4; ++t) wsc[t] = wscale[t * 16 + lo];

    __syncthreads();                       // all waves done reading W frags
    float* ldsf = reinterpret_cast<float*>(lds);
    const int rbase = wave * 2048;
    // C/D layout: col = lane&15 (o), row = (lane>>4)*4 + r (cell) [m89/m101]
    #pragma unroll
    for (int m = 0; m < 2; ++m)
        #pragma unroll
        for (int t = 0; t < 4; ++t)
            #pragma unroll
            for (int r = 0; r < 4; ++r)
                ldsf[rbase + (m * 16 + hi * 4 + r) * 64 + t * 16 + lo] =
                        acc[m][t][r] * wsc[t];
    __syncthreads();
    #pragma unroll
    for (int p = 0; p < 8; ++p) {
        const int f = p * 256 + lane * 4;
        f32x4 v = *reinterpret_cast<const f32x4*>(&ldsf[rbase + f]);
        *reinterpret_cast<f32x4*>(&out[(size_t)wcell * F + f]) = v;
    }
}

// ---------------- correctness-only fallback (no workspace) ----------------
__global__ void naive_kernel(const float* __restrict__ x,
                             const int* __restrict__ adjc,
                             const float* __restrict__ W,
                             float* __restrict__ out) {
    int n = blockIdx.x;
    int o = threadIdx.x;  // 64 threads
    float acc = 0.f;
    for (int j = 0; j < NH; ++j) {
        int idx = adjc[(size_t)n * NH + j];
        for (int f = 0; f < F; ++f)
            acc += x[(size_t)idx * F + f] * W[(size_t)(j * F + f) * F + o];
    }
    out[(size_t)n * F + o] = acc;
}

extern "C" void kernel_launch(void* const* d_in, const int* in_sizes, int n_in,
                              void* d_out, int out_size, void* d_ws, size_t ws_size,
                              hipStream_t stream) {
    const float* x    = (const float*)d_in[0];
    const int*   adjc = (const int*)d_in[1];
    const float* W    = (const float*)d_in[2];
    float* out = (float*)d_out;

    const size_t need_xq = (size_t)N_CELLS * F;              // 12.58 MB
    const size_t need_s  = (size_t)N_CELLS * sizeof(float);  // 0.79 MB
    const size_t need_wq = WQ_BYTES;                         // 36 KB
    const size_t need_ws = 64 * sizeof(float);               // 256 B

    if (ws_size >= need_xq + need_s + need_wq + need_ws) {
        signed char*   xq  = (signed char*)d_ws;
        float*         st  = (float*)((char*)d_ws + need_xq);
        unsigned char* wqp = (unsigned char*)((char*)d_ws + need_xq + need_s);
        float*         wsp = (float*)((char*)d_ws + need_xq + need_s + need_wq);
        convert_x_i8<<<(N_CELLS * 16) / 256, 256, 0, stream>>>(x, xq, st);
        convert_wscale<<<1, 256, 0, stream>>>(W, wsp);
        convert_wq<<<(NFRAG * 64) / 256, 256, 0, stream>>>(W, wsp, wqp);
        fused_gather_gemm_v10<<<N_CELLS / 256, BLOCK, 0, stream>>>(
                xq, st, adjc, wqp, wsp, out);
    } else {
        naive_kernel<<<N_CELLS, F, 0, stream>>>(x, adjc, W, out);
    }
}

// Round 11
// 141.226 us; speedup vs baseline: 1.0264x; 1.0264x over previous
//
#include <hip/hip_runtime.h>
#include <hip/hip_bf16.h>
#include <stdint.h>

#define N_CELLS 196608
#define NH 9
#define F 64            // F_IN == F_OUT == 64
#define K_TOT (NH * F)  // 576
#define BLOCK 512       // 8 waves, 32 cells per wave, 256 cells/block
#define NFRAG (NH * 4)  // 36 B-fragments (j, t)
#define WQ_BYTES (NFRAG * 64 * 16)   // 36864 B
#define LDS_BYTES 65536              // 36KB W + reuse as 64KB epilogue buffer

typedef __attribute__((ext_vector_type(4))) int   i32x4;
typedef __attribute__((ext_vector_type(4))) float f32x4;

// ---------------- x: fp32 -> int8 codes + per-row fp32 scale ---------------
// Plain row layout: byte k = feature k. Row = 64 B = one cache line.
__global__ __launch_bounds__(256) void convert_x_i8(
        const float* __restrict__ x, signed char* __restrict__ xq,
        float* __restrict__ stab) {
    int gid = blockIdx.x * blockDim.x + threadIdx.x;
    int row = gid >> 4;
    int k   = (gid & 15) * 4;
    f32x4 v = *reinterpret_cast<const f32x4*>(x + (size_t)row * F + k);
    float m = fmaxf(fmaxf(fabsf(v[0]), fabsf(v[1])),
                    fmaxf(fabsf(v[2]), fabsf(v[3])));
    #pragma unroll
    for (int d = 1; d < 16; d <<= 1) m = fmaxf(m, __shfl_xor(m, d, 64));
    float rs = (m > 0.f) ? 127.0f / m : 0.f;
    unsigned int d = 0;
    #pragma unroll
    for (int q = 0; q < 4; ++q) {
        int qi = (int)rintf(v[q] * rs);
        d |= ((unsigned int)(qi & 0xff)) << (q * 8);
    }
    *reinterpret_cast<unsigned int*>(xq + (size_t)row * F + k) = d;
    if ((gid & 15) == 0) stab[row] = m * (1.0f / 127.0f);
}

// ---------------- W per-column max -> wscale[64] ---------------------------
__global__ __launch_bounds__(256) void convert_wscale(
        const float* __restrict__ W, float* __restrict__ wscale) {
    __shared__ float mx[64];
    int o = threadIdx.x & 63, chunk = threadIdx.x >> 6;  // 4 threads per col
    if (threadIdx.x < 64) mx[threadIdx.x] = 0.f;
    __syncthreads();
    float m = 0.f;
    for (int k = chunk * 144; k < (chunk + 1) * 144; ++k)
        m = fmaxf(m, fabsf(W[(size_t)k * F + o]));
    atomicMax(reinterpret_cast<int*>(&mx[o]), __float_as_int(m));  // m >= 0
    __syncthreads();
    if (threadIdx.x < 64) wscale[threadIdx.x] = mx[threadIdx.x] * (1.0f / 127.0f);
}

// ---------------- W -> int8 MFMA B-fragment layout -------------------------
// frag id = j*4 + t. Lane l holds 16 bytes: wq[k = j*64 + (l>>4)*16 + b]
// [o = t*16 + (l&15)], b = 0..15.
__global__ __launch_bounds__(256) void convert_wq(
        const float* __restrict__ W, const float* __restrict__ wscale,
        unsigned char* __restrict__ wq) {
    int gid = blockIdx.x * blockDim.x + threadIdx.x;  // 0..2303
    int l = gid & 63, fid = gid >> 6;                 // fid 0..35
    int j = fid >> 2, t = fid & 3;
    int hi = l >> 4, lo = l & 15;
    int o = t * 16 + lo;
    float ws = wscale[o];
    float inv = (ws > 0.f) ? 1.0f / ws : 0.f;
    unsigned int dw[4];
    #pragma unroll
    for (int w = 0; w < 4; ++w) {
        unsigned int d = 0;
        #pragma unroll
        for (int b = 0; b < 4; ++b) {
            int k = j * 64 + hi * 16 + w * 4 + b;
            int qi = (int)rintf(W[(size_t)k * F + o] * inv);
            d |= ((unsigned int)(qi & 0xff)) << (b * 8);
        }
        dw[w] = d;
    }
    *reinterpret_cast<uint4*>(wq + (size_t)gid * 16) =
        make_uint4(dw[0], dw[1], dw[2], dw[3]);
}

// ---------------- fused gather + GEMM, v11 ---------------------------------
// v10 post-mortem: right structure, but VGPR hit the (512,2) 128-cap and
// spilled (WRITE 222MB scratch). v11: __launch_bounds__(512,1) -> 256-VGPR
// cap (8 waves/CU worst case -- v8 proved 8 vs 16 waves is identical), and
// the freed headroom buys a DEPTH-4 gather ring (8 lines in flight/wave,
// ~64/CU) with per-row scales riding the same ring (sS, L2-hot 4B loads).
// Dequant stays post-MFMA (v9 showed pre-MFMA expand serializes).
__global__ __launch_bounds__(BLOCK, 1) void fused_gather_gemm_v11(
        const signed char* __restrict__ xq, const float* __restrict__ stab,
        const int* __restrict__ adjc, const unsigned char* __restrict__ wq,
        const float* __restrict__ wscale, float* __restrict__ out) {
    __shared__ __align__(16) unsigned char lds[LDS_BYTES];

    const int wave = threadIdx.x >> 6;
    const int lane = threadIdx.x & 63;
    const int lo = lane & 15, hi = lane >> 4;
    const int wcell = blockIdx.x * 256 + wave * 32;  // wave's 32 cells

    // --- neighbor indices (scales are loaded through the ring instead)
    int idx[2][NH];
    #pragma unroll
    for (int m = 0; m < 2; ++m) {
        const int* ap = adjc + (size_t)(wcell + m * 16 + lo) * NH;
        #pragma unroll
        for (int j = 0; j < NH; ++j) idx[m][j] = __builtin_nontemporal_load(ap + j);
    }

    // one 16B load = lane's complete A-fragment (k = hi*16 .. hi*16+15)
    auto loadA = [&](int m, int j) -> i32x4 {
        return *reinterpret_cast<const i32x4*>(
                xq + (size_t)idx[m][j] * F + hi * 16);
    };

    // --- stage W fragments into LDS (2304 x 16B, coalesced)
    {
        const i32x4* src = reinterpret_cast<const i32x4*>(wq);
        i32x4* dst = reinterpret_cast<i32x4*>(lds);
        #pragma unroll
        for (int it = 0; it < 5; ++it) {
            int i = it * BLOCK + threadIdx.x;
            if (i < NFRAG * 64) dst[i] = src[i];
        }
    }

    // --- depth-4 ring prologue: issue slices j = 0..3 (data + scale)
    i32x4 aS[5][2];
    float sS[5][2];
    #pragma unroll
    for (int s = 0; s < 4; ++s)
        #pragma unroll
        for (int m = 0; m < 2; ++m) {
            aS[s][m] = loadA(m, s);
            sS[s][m] = stab[idx[m][s]];
        }
    __syncthreads();

    f32x4 acc[2][4];
    #pragma unroll
    for (int m = 0; m < 2; ++m)
        #pragma unroll
        for (int t = 0; t < 4; ++t) acc[m][t] = f32x4{0.f, 0.f, 0.f, 0.f};

    const i32x4* wl = reinterpret_cast<const i32x4*>(lds);
    const int sbase = (lane >> 4) * 20;  // hi*16 + hi*4: shfl src for row hi*4+r

    #pragma unroll
    for (int j = 0; j < NH; ++j) {
        const int cur = j % 5;            // compile-time after full unroll
        const int nx4 = (j + 4) % 5;
        if (j + 4 < NH) {                 // issue slice j+4 (2 gathers + 2 scales)
            #pragma unroll
            for (int m = 0; m < 2; ++m) {
                aS[nx4][m] = loadA(m, j + 4);
                sS[nx4][m] = stab[idx[m][j + 4]];
            }
        }
        __builtin_amdgcn_sched_barrier(0);   // loads issued above stay above

        // scales for this j in C/D layout: row = hi*4 + r
        float sd[2][4];
        #pragma unroll
        for (int m = 0; m < 2; ++m)
            #pragma unroll
            for (int r = 0; r < 4; ++r)
                sd[m][r] = __shfl(sS[cur][m], sbase + r, 64);

        #pragma unroll
        for (int t = 0; t < 4; ++t) {
            i32x4 b = wl[(j * 4 + t) * 64 + lane];   // ds_read_b128
            #pragma unroll
            for (int m = 0; m < 2; ++m) {
                i32x4 iz = {0, 0, 0, 0};
                i32x4 iacc = __builtin_amdgcn_mfma_i32_16x16x64_i8(
                        aS[cur][m], b, iz, 0, 0, 0);
                #pragma unroll
                for (int r = 0; r < 4; ++r)
                    acc[m][t][r] += sd[m][r] * (float)iacc[r];  // post-MFMA dequant
            }
        }
        __builtin_amdgcn_sched_barrier(0);   // MFMAs can't float up
    }

    // --- epilogue: x wscale[o], transpose through LDS, 1KB coalesced stores
    float wsc[4];
    #pragma unroll
    for (int t = 0; t < 4; ++t) wsc[t] = wscale[t * 16 + lo];

    __syncthreads();                       // all waves done reading W frags
    float* ldsf = reinterpret_cast<float*>(lds);
    const int rbase = wave * 2048;
    // C/D layout: col = lane&15 (o), row = (lane>>4)*4 + r (cell) [m89/m101]
    #pragma unroll
    for (int m = 0; m < 2; ++m)
        #pragma unroll
        for (int t = 0; t < 4; ++t)
            #pragma unroll
            for (int r = 0; r < 4; ++r)
                ldsf[rbase + (m * 16 + hi * 4 + r) * 64 + t * 16 + lo] =
                        acc[m][t][r] * wsc[t];
    __syncthreads();
    #pragma unroll
    for (int p = 0; p < 8; ++p) {
        const int f = p * 256 + lane * 4;
        f32x4 v = *reinterpret_cast<const f32x4*>(&ldsf[rbase + f]);
        *reinterpret_cast<f32x4*>(&out[(size_t)wcell * F + f]) = v;
    }
}

// ---------------- correctness-only fallback (no workspace) ----------------
__global__ void naive_kernel(const float* __restrict__ x,
                             const int* __restrict__ adjc,
                             const float* __restrict__ W,
                             float* __restrict__ out) {
    int n = blockIdx.x;
    int o = threadIdx.x;  // 64 threads
    float acc = 0.f;
    for (int j = 0; j < NH; ++j) {
        int idx = adjc[(size_t)n * NH + j];
        for (int f = 0; f < F; ++f)
            acc += x[(size_t)idx * F + f] * W[(size_t)(j * F + f) * F + o];
    }
    out[(size_t)n * F + o] = acc;
}

extern "C" void kernel_launch(void* const* d_in, const int* in_sizes, int n_in,
                              void* d_out, int out_size, void* d_ws, size_t ws_size,
                              hipStream_t stream) {
    const float* x    = (const float*)d_in[0];
    const int*   adjc = (const int*)d_in[1];
    const float* W    = (const float*)d_in[2];
    float* out = (float*)d_out;

    const size_t need_xq = (size_t)N_CELLS * F;              // 12.58 MB
    const size_t need_s  = (size_t)N_CELLS * sizeof(float);  // 0.79 MB
    const size_t need_wq = WQ_BYTES;                         // 36 KB
    const size_t need_ws = 64 * sizeof(float);               // 256 B

    if (ws_size >= need_xq + need_s + need_wq + need_ws) {
        signed char*   xq  = (signed char*)d_ws;
        float*         st  = (float*)((char*)d_ws + need_xq);
        unsigned char* wqp = (unsigned char*)((char*)d_ws + need_xq + need_s);
        float*         wsp = (float*)((char*)d_ws + need_xq + need_s + need_wq);
        convert_x_i8<<<(N_CELLS * 16) / 256, 256, 0, stream>>>(x, xq, st);
        convert_wscale<<<1, 256, 0, stream>>>(W, wsp);
        convert_wq<<<(NFRAG * 64) / 256, 256, 0, stream>>>(W, wsp, wqp);
        fused_gather_gemm_v11<<<N_CELLS / 256, BLOCK, 0, stream>>>(
                xq, st, adjc, wqp, wsp, out);
    } else {
        naive_kernel<<<N_CELLS, F, 0, stream>>>(x, adjc, W, out);
    }
}

// Round 12
// 130.530 us; speedup vs baseline: 1.1105x; 1.0819x over previous
//
#include <hip/hip_runtime.h>
#include <hip/hip_bf16.h>
#include <stdint.h>

#define N_CELLS 196608
#define NH 9
#define F 64            // F_IN == F_OUT == 64
#define K_TOT (NH * F)  // 576
#define BLOCK 512       // 8 waves, 32 cells per wave, 256 cells/block
#define NFRAG (NH * 4)  // 36 B-fragments (j, t)
#define WQ_BYTES (NFRAG * 64 * 16)   // 36864 B
// LDS: W frags [0, 36864) + epilogue floats [36864, 36864+65536).
// Total 100 KB > 80 KB ON PURPOSE: forces 1 block/CU, so the backend's
// occupancy-matched VGPR budget becomes 256 (v7/v10/v11 post-mortem: at
// 64-72KB LDS -> 2 blocks/CU -> budget 128 -> unavoidable spills).
#define LDS_BYTES (WQ_BYTES + 65536)

typedef __attribute__((ext_vector_type(4))) int   i32x4;
typedef __attribute__((ext_vector_type(4))) float f32x4;

// ---------------- x: fp32 -> int8 codes + per-row fp32 scale ---------------
// Plain row layout: byte k = feature k. Row = 64 B = one cache line.
__global__ __launch_bounds__(256) void convert_x_i8(
        const float* __restrict__ x, signed char* __restrict__ xq,
        float* __restrict__ stab) {
    int gid = blockIdx.x * blockDim.x + threadIdx.x;
    int row = gid >> 4;
    int k   = (gid & 15) * 4;
    f32x4 v = *reinterpret_cast<const f32x4*>(x + (size_t)row * F + k);
    float m = fmaxf(fmaxf(fabsf(v[0]), fabsf(v[1])),
                    fmaxf(fabsf(v[2]), fabsf(v[3])));
    #pragma unroll
    for (int d = 1; d < 16; d <<= 1) m = fmaxf(m, __shfl_xor(m, d, 64));
    float rs = (m > 0.f) ? 127.0f / m : 0.f;
    unsigned int d = 0;
    #pragma unroll
    for (int q = 0; q < 4; ++q) {
        int qi = (int)rintf(v[q] * rs);
        d |= ((unsigned int)(qi & 0xff)) << (q * 8);
    }
    *reinterpret_cast<unsigned int*>(xq + (size_t)row * F + k) = d;
    if ((gid & 15) == 0) stab[row] = m * (1.0f / 127.0f);
}

// ---------------- W per-column max -> wscale[64] ---------------------------
__global__ __launch_bounds__(256) void convert_wscale(
        const float* __restrict__ W, float* __restrict__ wscale) {
    __shared__ float mx[64];
    int o = threadIdx.x & 63, chunk = threadIdx.x >> 6;  // 4 threads per col
    if (threadIdx.x < 64) mx[threadIdx.x] = 0.f;
    __syncthreads();
    float m = 0.f;
    for (int k = chunk * 144; k < (chunk + 1) * 144; ++k)
        m = fmaxf(m, fabsf(W[(size_t)k * F + o]));
    atomicMax(reinterpret_cast<int*>(&mx[o]), __float_as_int(m));  // m >= 0
    __syncthreads();
    if (threadIdx.x < 64) wscale[threadIdx.x] = mx[threadIdx.x] * (1.0f / 127.0f);
}

// ---------------- W -> int8 MFMA B-fragment layout -------------------------
// frag id = j*4 + t. Lane l holds 16 bytes: wq[k = j*64 + (l>>4)*16 + b]
// [o = t*16 + (l&15)], b = 0..15.
__global__ __launch_bounds__(256) void convert_wq(
        const float* __restrict__ W, const float* __restrict__ wscale,
        unsigned char* __restrict__ wq) {
    int gid = blockIdx.x * blockDim.x + threadIdx.x;  // 0..2303
    int l = gid & 63, fid = gid >> 6;                 // fid 0..35
    int j = fid >> 2, t = fid & 3;
    int hi = l >> 4, lo = l & 15;
    int o = t * 16 + lo;
    float ws = wscale[o];
    float inv = (ws > 0.f) ? 1.0f / ws : 0.f;
    unsigned int dw[4];
    #pragma unroll
    for (int w = 0; w < 4; ++w) {
        unsigned int d = 0;
        #pragma unroll
        for (int b = 0; b < 4; ++b) {
            int k = j * 64 + hi * 16 + w * 4 + b;
            int qi = (int)rintf(W[(size_t)k * F + o] * inv);
            d |= ((unsigned int)(qi & 0xff)) << (b * 8);
        }
        dw[w] = d;
    }
    *reinterpret_cast<uint4*>(wq + (size_t)gid * 16) =
        make_uint4(dw[0], dw[1], dw[2], dw[3]);
}

// ---------------- fused gather + GEMM, v12 ---------------------------------
// = v11 structure (direct int8 MFMA, depth-4 fenced ring, post-MFMA dequant)
// with the register budget actually lifted: LDS padded past 80KB -> 1
// block/CU -> backend VGPR budget 256 -> no spills. 8 waves/CU occupancy
// (proven perf-equivalent to 16 by v6-vs-v8). 64 gather lines in flight/CU.
__global__ __launch_bounds__(BLOCK) void fused_gather_gemm_v12(
        const signed char* __restrict__ xq, const float* __restrict__ stab,
        const int* __restrict__ adjc, const unsigned char* __restrict__ wq,
        const float* __restrict__ wscale, float* __restrict__ out) {
    __shared__ __align__(16) unsigned char lds[LDS_BYTES];

    const int wave = threadIdx.x >> 6;
    const int lane = threadIdx.x & 63;
    const int lo = lane & 15, hi = lane >> 4;
    const int wcell = blockIdx.x * 256 + wave * 32;  // wave's 32 cells

    // --- neighbor indices (scales ride the ring)
    int idx[2][NH];
    #pragma unroll
    for (int m = 0; m < 2; ++m) {
        const int* ap = adjc + (size_t)(wcell + m * 16 + lo) * NH;
        #pragma unroll
        for (int j = 0; j < NH; ++j) idx[m][j] = __builtin_nontemporal_load(ap + j);
    }

    // one 16B load = lane's complete A-fragment (k = hi*16 .. hi*16+15)
    auto loadA = [&](int m, int j) -> i32x4 {
        return *reinterpret_cast<const i32x4*>(
                xq + (size_t)idx[m][j] * F + hi * 16);
    };

    // --- stage W fragments into LDS (2304 x 16B, coalesced)
    {
        const i32x4* src = reinterpret_cast<const i32x4*>(wq);
        i32x4* dst = reinterpret_cast<i32x4*>(lds);
        #pragma unroll
        for (int it = 0; it < 5; ++it) {
            int i = it * BLOCK + threadIdx.x;
            if (i < NFRAG * 64) dst[i] = src[i];
        }
    }

    // --- depth-4 ring prologue: issue slices j = 0..3 (data + scale)
    i32x4 aS[5][2];
    float sS[5][2];
    #pragma unroll
    for (int s = 0; s < 4; ++s)
        #pragma unroll
        for (int m = 0; m < 2; ++m) {
            aS[s][m] = loadA(m, s);
            sS[s][m] = stab[idx[m][s]];
        }
    __syncthreads();

    f32x4 acc[2][4];
    #pragma unroll
    for (int m = 0; m < 2; ++m)
        #pragma unroll
        for (int t = 0; t < 4; ++t) acc[m][t] = f32x4{0.f, 0.f, 0.f, 0.f};

    const i32x4* wl = reinterpret_cast<const i32x4*>(lds);
    const int sbase = (lane >> 4) * 20;  // hi*16 + hi*4: shfl src for row hi*4+r

    #pragma unroll
    for (int j = 0; j < NH; ++j) {
        const int cur = j % 5;            // compile-time after full unroll
        const int nx4 = (j + 4) % 5;
        if (j + 4 < NH) {                 // issue slice j+4 (2 gathers + 2 scales)
            #pragma unroll
            for (int m = 0; m < 2; ++m) {
                aS[nx4][m] = loadA(m, j + 4);
                sS[nx4][m] = stab[idx[m][j + 4]];
            }
        }
        __builtin_amdgcn_sched_barrier(0);   // loads issued above stay above

        // scales for this j in C/D layout: row = hi*4 + r
        float sd[2][4];
        #pragma unroll
        for (int m = 0; m < 2; ++m)
            #pragma unroll
            for (int r = 0; r < 4; ++r)
                sd[m][r] = __shfl(sS[cur][m], sbase + r, 64);

        #pragma unroll
        for (int t = 0; t < 4; ++t) {
            i32x4 b = wl[(j * 4 + t) * 64 + lane];   // ds_read_b128
            #pragma unroll
            for (int m = 0; m < 2; ++m) {
                i32x4 iz = {0, 0, 0, 0};
                i32x4 iacc = __builtin_amdgcn_mfma_i32_16x16x64_i8(
                        aS[cur][m], b, iz, 0, 0, 0);
                #pragma unroll
                for (int r = 0; r < 4; ++r)
                    acc[m][t][r] += sd[m][r] * (float)iacc[r];  // post-MFMA dequant
            }
        }
        __builtin_amdgcn_sched_barrier(0);   // MFMAs can't float up
    }

    // --- epilogue: x wscale[o], transpose through PRIVATE LDS region,
    //     1KB coalesced stores (no W-region reuse -> no extra barrier needed,
    //     but keep one for safety; it's once per kernel)
    float wsc[4];
    #pragma unroll
    for (int t = 0; t < 4; ++t) wsc[t] = wscale[t * 16 + lo];

    float* ldsf = reinterpret_cast<float*>(lds + WQ_BYTES);
    const int rbase = wave * 2048;
    // C/D layout: col = lane&15 (o), row = (lane>>4)*4 + r (cell) [m89/m101]
    #pragma unroll
    for (int m = 0; m < 2; ++m)
        #pragma unroll
        for (int t = 0; t < 4; ++t)
            #pragma unroll
            for (int r = 0; r < 4; ++r)
                ldsf[rbase + (m * 16 + hi * 4 + r) * 64 + t * 16 + lo] =
                        acc[m][t][r] * wsc[t];
    __syncthreads();
    #pragma unroll
    for (int p = 0; p < 8; ++p) {
        const int f = p * 256 + lane * 4;
        f32x4 v = *reinterpret_cast<const f32x4*>(&ldsf[rbase + f]);
        *reinterpret_cast<f32x4*>(&out[(size_t)wcell * F + f]) = v;
    }
}

// ---------------- correctness-only fallback (no workspace) ----------------
__global__ void naive_kernel(const float* __restrict__ x,
                             const int* __restrict__ adjc,
                             const float* __restrict__ W,
                             float* __restrict__ out) {
    int n = blockIdx.x;
    int o = threadIdx.x;  // 64 threads
    float acc = 0.f;
    for (int j = 0; j < NH; ++j) {
        int idx = adjc[(size_t)n * NH + j];
        for (int f = 0; f < F; ++f)
            acc += x[(size_t)idx * F + f] * W[(size_t)(j * F + f) * F + o];
    }
    out[(size_t)n * F + o] = acc;
}

extern "C" void kernel_launch(void* const* d_in, const int* in_sizes, int n_in,
                              void* d_out, int out_size, void* d_ws, size_t ws_size,
                              hipStream_t stream) {
    const float* x    = (const float*)d_in[0];
    const int*   adjc = (const int*)d_in[1];
    const float* W    = (const float*)d_in[2];
    float* out = (float*)d_out;

    const size_t need_xq = (size_t)N_CELLS * F;              // 12.58 MB
    const size_t need_s  = (size_t)N_CELLS * sizeof(float);  // 0.79 MB
    const size_t need_wq = WQ_BYTES;                         // 36 KB
    const size_t need_ws = 64 * sizeof(float);               // 256 B

    if (ws_size >= need_xq + need_s + need_wq + need_ws) {
        signed char*   xq  = (signed char*)d_ws;
        float*         st  = (float*)((char*)d_ws + need_xq);
        unsigned char* wqp = (unsigned char*)((char*)d_ws + need_xq + need_s);
        float*         wsp = (float*)((char*)d_ws + need_xq + need_s + need_wq);
        convert_x_i8<<<(N_CELLS * 16) / 256, 256, 0, stream>>>(x, xq, st);
        convert_wscale<<<1, 256, 0, stream>>>(W, wsp);
        convert_wq<<<(NFRAG * 64) / 256, 256, 0, stream>>>(W, wsp, wqp);
        fused_gather_gemm_v12<<<N_CELLS / 256, BLOCK, 0, stream>>>(
                xq, st, adjc, wqp, wsp, out);
    } else {
        naive_kernel<<<N_CELLS, F, 0, stream>>>(x, adjc, W, out);
    }
}